// Round 1
// baseline (688.790 us; speedup 1.0000x reference)
//
#include <hip/hip_runtime.h>
#include <hip/hip_bf16.h>
#include <stdint.h>

#define D_IN   2048
#define D_SAE  32768
#define K_NNZ  64

// ---------------------------------------------------------------------------
// Phase 1: W (D_IN x D_SAE) fp32 row-major  ->  W_T (D_SAE x D_IN) bf16
// 64x64 tile via LDS, 256 threads/block. Reads coalesced along s, writes
// coalesced along d. LDS pitch 65 -> (dl + sl) % 32 bank mapping, 2-way max
// (free on gfx950, m136).
// ---------------------------------------------------------------------------
__global__ __launch_bounds__(256) void transpose_to_bf16(
    const float* __restrict__ W, __hip_bfloat16* __restrict__ WT) {
  __shared__ float tile[64][65];
  const int s0 = blockIdx.x * 64;   // along D_SAE
  const int d0 = blockIdx.y * 64;   // along D_IN
  const int tid = threadIdx.x;

  // Load: r -> d, c -> s (contiguous). float4 per thread, 4 iterations.
  {
    const int c = (tid & 15) * 4;
    const int rbase = tid >> 4;       // 0..15
#pragma unroll
    for (int i = 0; i < 4; ++i) {
      const int rr = rbase + i * 16;  // 0..63
      const float4 v = *reinterpret_cast<const float4*>(
          &W[(size_t)(d0 + rr) * D_SAE + (size_t)(s0 + c)]);
      tile[rr][c + 0] = v.x;
      tile[rr][c + 1] = v.y;
      tile[rr][c + 2] = v.z;
      tile[rr][c + 3] = v.w;
    }
  }
  __syncthreads();

  // Write: lanes along d (contiguous bf16), loop over s.
  {
    const int dl = tid & 63;
    const int sbase = tid >> 6;       // 0..3
#pragma unroll
    for (int j = 0; j < 16; ++j) {
      const int sl = sbase + j * 4;   // 0..63
      WT[(size_t)(s0 + sl) * D_IN + (size_t)(d0 + dl)] =
          __float2bfloat16(tile[dl][sl]);
    }
  }
}

// ---------------------------------------------------------------------------
// Phase 2: one block per row. 256 threads, each owns 8 contiguous d.
// Per k: broadcast (idx, v) from LDS, each lane does one 16B (8x bf16) load
// from W_T row idx, unpack via shift, fp32 FMA accumulate.
// Dedup first (scatter .set semantics = last write wins).
// ---------------------------------------------------------------------------
__global__ __launch_bounds__(256) void sae_decode(
    const int* __restrict__ indices, const float* __restrict__ values,
    const __hip_bfloat16* __restrict__ WT, const float* __restrict__ bias,
    float* __restrict__ out) {
  const int row = blockIdx.x;
  const int tid = threadIdx.x;

  __shared__ int   s_idx[K_NNZ];
  __shared__ float s_val[K_NNZ];

  if (tid < K_NNZ) {
    s_idx[tid] = indices[row * K_NNZ + tid];
    s_val[tid] = values[row * K_NNZ + tid];
  }
  __syncthreads();
  // Last-write-wins: zero v[k] if a later k' has the same index.
  if (tid < K_NNZ) {
    const int my = s_idx[tid];
    for (int k2 = tid + 1; k2 < K_NNZ; ++k2) {
      if (s_idx[k2] == my) { s_val[tid] = 0.0f; break; }
    }
  }
  __syncthreads();

  const int d0 = tid * 8;
  float acc[8];
  {
    const float4 b0 = *reinterpret_cast<const float4*>(&bias[d0]);
    const float4 b1 = *reinterpret_cast<const float4*>(&bias[d0 + 4]);
    acc[0] = b0.x; acc[1] = b0.y; acc[2] = b0.z; acc[3] = b0.w;
    acc[4] = b1.x; acc[5] = b1.y; acc[6] = b1.z; acc[7] = b1.w;
  }

#pragma unroll 4
  for (int k = 0; k < K_NNZ; ++k) {
    const float v = s_val[k];
    const int idx = s_idx[k];
    const uint4 w = *reinterpret_cast<const uint4*>(
        &WT[(size_t)idx * D_IN + d0]);
#pragma unroll
    for (int j = 0; j < 4; ++j) {
      const uint32_t u = (&w.x)[j];
      const float lo = __uint_as_float(u << 16);
      const float hi = __uint_as_float(u & 0xffff0000u);
      acc[2 * j + 0] = fmaf(v, lo, acc[2 * j + 0]);
      acc[2 * j + 1] = fmaf(v, hi, acc[2 * j + 1]);
    }
  }

  float4* o = reinterpret_cast<float4*>(&out[(size_t)row * D_IN + d0]);
  o[0] = make_float4(acc[0], acc[1], acc[2], acc[3]);
  o[1] = make_float4(acc[4], acc[5], acc[6], acc[7]);
}

// ---------------------------------------------------------------------------
// Fallback (workspace too small): gather directly from fp32 W (strided —
// slow but correct). Insurance only.
// ---------------------------------------------------------------------------
__global__ __launch_bounds__(256) void sae_decode_direct(
    const int* __restrict__ indices, const float* __restrict__ values,
    const float* __restrict__ W, const float* __restrict__ bias,
    float* __restrict__ out) {
  const int row = blockIdx.x;
  const int tid = threadIdx.x;

  __shared__ int   s_idx[K_NNZ];
  __shared__ float s_val[K_NNZ];
  if (tid < K_NNZ) {
    s_idx[tid] = indices[row * K_NNZ + tid];
    s_val[tid] = values[row * K_NNZ + tid];
  }
  __syncthreads();
  if (tid < K_NNZ) {
    const int my = s_idx[tid];
    for (int k2 = tid + 1; k2 < K_NNZ; ++k2) {
      if (s_idx[k2] == my) { s_val[tid] = 0.0f; break; }
    }
  }
  __syncthreads();

  const int d0 = tid * 8;
  float acc[8];
#pragma unroll
  for (int j = 0; j < 8; ++j) acc[j] = bias[d0 + j];

  for (int k = 0; k < K_NNZ; ++k) {
    const float v = s_val[k];
    const int idx = s_idx[k];
#pragma unroll
    for (int j = 0; j < 8; ++j) {
      acc[j] = fmaf(v, W[(size_t)(d0 + j) * D_SAE + idx], acc[j]);
    }
  }
  float4* o = reinterpret_cast<float4*>(&out[(size_t)row * D_IN + d0]);
  o[0] = make_float4(acc[0], acc[1], acc[2], acc[3]);
  o[1] = make_float4(acc[4], acc[5], acc[6], acc[7]);
}

extern "C" void kernel_launch(void* const* d_in, const int* in_sizes, int n_in,
                              void* d_out, int out_size, void* d_ws, size_t ws_size,
                              hipStream_t stream) {
  const int*   indices = (const int*)d_in[0];
  const float* values  = (const float*)d_in[1];
  const float* W       = (const float*)d_in[2];
  const float* bias    = (const float*)d_in[3];
  float* out = (float*)d_out;

  const int n_rows = in_sizes[0] / K_NNZ;  // 8192
  const size_t wt_bytes = (size_t)D_SAE * D_IN * sizeof(__hip_bfloat16);  // 128 MB

  if (ws_size >= wt_bytes) {
    __hip_bfloat16* WT = (__hip_bfloat16*)d_ws;
    dim3 g1(D_SAE / 64, D_IN / 64);  // 512 x 32
    transpose_to_bf16<<<g1, 256, 0, stream>>>(W, WT);
    sae_decode<<<n_rows, 256, 0, stream>>>(indices, values, WT, bias, out);
  } else {
    sae_decode_direct<<<n_rows, 256, 0, stream>>>(indices, values, W, bias, out);
  }
}